// Round 4
// baseline (231.726 us; speedup 1.0000x reference)
//
#include <hip/hip_runtime.h>

// Head: fused single-head causal attention. Round 8: clean occupancy test.
// Round 7 bundled occupancy 2->3 waves/SIMD with rolling weight reloads; the
// reloads put a dependent L2-latency wait before every MFMA group and it
// regressed. Round 8 isolates occupancy: weights back to 24 RESIDENT frags
// (loaded once, 96 VGPR), x staging shrunk to a single half-tile buffer
// (tf[4], 16 VGPR) so peak alloc ~160 fits __launch_bounds__(64,3).
// LDS stays 12032 B (no qs; q transposed through ps scratch into register
// A-frags). -> 12 one-wave blocks/CU (VGPR 3/SIMD, LDS allows 13).
// Per-wave load lookahead is only ~1 half-tile; the added TLP (12 waves/CU
// vs 8) is what's being tested as the latency-hiding mechanism.
// Softmax: no max-sub (|s|<~3), scale folded into Wq; denominator via
// ones-column MFMA row-sum; P stored unnormalized, O divided at the end.
//
// mfma_f32_16x16x32_bf16 layouts (HW-verified, guide §3):
//   A-frag: A[m = lane&15][k = quad*8 + j]
//   B-frag: B[k = quad*8 + j][n = lane&15]
//   C/D   : col = lane&15, row = quad*4 + reg

#define TT 64
#define CC 128
#define HD 32

typedef __bf16 bf16_t;
typedef __bf16 bf8_t __attribute__((ext_vector_type(8)));
typedef __bf16 bf4_t __attribute__((ext_vector_type(4)));
typedef float  f4_t  __attribute__((ext_vector_type(4)));

// d_ws: wf[(n6*4 + kk)*64 + lane] = 16-byte bf8 B-frag.
// n6 = 0..5 (q lo/hi, k lo/hi, v lo/hi), kk = 0..3 (K blocks of 32).
// Element j = Wsel[(kk*32 + (lane>>4)*8 + j)][(n6&1)*16 + (lane&15)].
// Q-frags (n6<2) pre-scaled by 1/sqrt(32).
__global__ __launch_bounds__(256) void prep_weights(
    const float* __restrict__ Wq, const float* __restrict__ Wk,
    const float* __restrict__ Wv, bf16_t* __restrict__ wf)
{
  int t = blockIdx.x * 256 + threadIdx.x;   // 0..12287
  int j    = t & 7;
  int lane = (t >> 3) & 63;
  int kt   = (t >> 9) & 3;
  int n6   = t >> 11;
  int k    = kt * 32 + (lane >> 4) * 8 + j;
  int col  = (n6 & 1) * 16 + (lane & 15);
  const float* W = (n6 >> 1) == 0 ? Wq : ((n6 >> 1) == 1 ? Wk : Wv);
  float v = W[k * HD + col];
  if (n6 < 2) v *= 0.17677669529663687f;    // fold 1/sqrt(32) into Wq
  wf[t] = (bf16_t)v;
}

__global__ __launch_bounds__(64, 3) void head_fused(
    const float* __restrict__ x, const bf8_t* __restrict__ wf,
    float* __restrict__ out)
{
  __shared__ __align__(16) bf16_t ks[TT][40];   // k[row][d]           5120 B
  __shared__ __align__(16) bf16_t vt[HD][72];   // v^T[d][row]         4608 B
  __shared__ __align__(16) bf16_t ps[16][72];   // q-scratch / P strip 2304 B
  // total 12032 B; 13 blocks/CU by LDS, 12 by VGPR (3 waves/SIMD)

  const int lane = threadIdx.x;      // 0..63, one wave
  const int quad = lane >> 4;
  const int l16  = lane & 15;
  const int b    = blockIdx.x;
  const float* __restrict__ xblk = x + (size_t)b * (TT * CC);
  float* __restrict__ ob = out + (size_t)b * (TT * HD);

  const f4_t zero4 = {0.f, 0.f, 0.f, 0.f};

  bf8_t wfr[24];                     // resident weight B-frags (96 VGPR)
  bf8_t aq[4];                       // q A-frags, register-resident (16 VGPR)
  float4 tf[4];                      // HALF-tile staging, fp32 (16 VGPR)

  // load half an x-tile (kk = 2h, 2h+1) into tf: 4x dwordx4
  auto load_half = [&](int i, int h) {
    #pragma unroll
    for (int u = 0; u < 2; ++u) {
      const float* s = xblk + (16 * i + l16) * CC + (2 * h + u) * 32 + quad * 8;
      tf[2 * u]     = *(const float4*)s;
      tf[2 * u + 1] = *(const float4*)(s + 4);
    }
  };
  auto cvt8 = [&](int u) -> bf8_t {  // u = 0/1: which kk-group within tf
    float4 f0 = tf[2 * u], f1 = tf[2 * u + 1];
    bf8_t a;
    a[0] = (bf16_t)f0.x; a[1] = (bf16_t)f0.y; a[2] = (bf16_t)f0.z; a[3] = (bf16_t)f0.w;
    a[4] = (bf16_t)f1.x; a[5] = (bf16_t)f1.y; a[6] = (bf16_t)f1.z; a[7] = (bf16_t)f1.w;
    return a;
  };

  // precondition: half (i,0) is in flight/in tf on entry.
  auto proj_tile = [&](int i) {
    f4_t acc[6];
    #pragma unroll
    for (int n = 0; n < 6; ++n) acc[n] = zero4;
    bf8_t a0 = cvt8(0), a1 = cvt8(1);     // waits on half (i,0)
    load_half(i, 1);                      // tf free -> issue half (i,1)
    #pragma unroll
    for (int n = 0; n < 6; ++n)
      acc[n] = __builtin_amdgcn_mfma_f32_16x16x32_bf16(a0, wfr[n * 4 + 0], acc[n], 0, 0, 0);
    #pragma unroll
    for (int n = 0; n < 6; ++n)
      acc[n] = __builtin_amdgcn_mfma_f32_16x16x32_bf16(a1, wfr[n * 4 + 1], acc[n], 0, 0, 0);
    bf8_t a2 = cvt8(0), a3 = cvt8(1);     // waits on half (i,1)
    if (i < 3) load_half(i + 1, 0);       // issue next tile's first half
    #pragma unroll
    for (int n = 0; n < 6; ++n)
      acc[n] = __builtin_amdgcn_mfma_f32_16x16x32_bf16(a2, wfr[n * 4 + 2], acc[n], 0, 0, 0);
    #pragma unroll
    for (int n = 0; n < 6; ++n)
      acc[n] = __builtin_amdgcn_mfma_f32_16x16x32_bf16(a3, wfr[n * 4 + 3], acc[n], 0, 0, 0);
    // stores: q -> ps scratch (transpose), k -> ks, v -> vt
    #pragma unroll
    for (int r = 0; r < 4; ++r) {
      int rl  = quad * 4 + r;                // C/D: row = quad*4 + reg
      int row = 16 * i + rl;
      ps[rl][l16]       = (bf16_t)acc[0][r];
      ps[rl][16 + l16]  = (bf16_t)acc[1][r];
      ks[row][l16]      = (bf16_t)acc[2][r];
      ks[row][16 + l16] = (bf16_t)acc[3][r];
    }
    bf4_t v0 = { (bf16_t)acc[4][0], (bf16_t)acc[4][1], (bf16_t)acc[4][2], (bf16_t)acc[4][3] };
    bf4_t v1 = { (bf16_t)acc[5][0], (bf16_t)acc[5][1], (bf16_t)acc[5][2], (bf16_t)acc[5][3] };
    *(bf4_t*)&vt[l16][16 * i + quad * 4]      = v0;   // tokens quad*4..+3 contiguous
    *(bf4_t*)&vt[16 + l16][16 * i + quad * 4] = v1;
    // q tile back out of scratch as A-frag (register-resident for phase 2)
    aq[i] = *(const bf8_t*)&ps[l16][quad * 8];
  };

  // scores -> exp (unnormalized, bf16) -> PV + ones-MFMA row-sum -> divide.
  // ps is reused as the P strip here (q-scratch use ended in phase 1).
  bf8_t ones8;
  #pragma unroll
  for (int t = 0; t < 8; ++t) ones8[t] = (bf16_t)1.0f;

  auto sm_tile = [&](int i) {
    f4_t sc[4];
    bf8_t aqv = aq[i];                       // scale pre-folded
    #pragma unroll
    for (int j = 0; j < 4; ++j) {
      sc[j] = zero4;
      if (j <= i) {
        bf8_t bk = *(const bf8_t*)&ks[16 * j + l16][quad * 8];
        sc[j] = __builtin_amdgcn_mfma_f32_16x16x32_bf16(aqv, bk, zero4, 0, 0, 0);
      }
    }
    #pragma unroll
    for (int r = 0; r < 4; ++r) {
      int rl = quad * 4 + r;
      #pragma unroll
      for (int j = 0; j < 4; ++j) {
        if (j <= i) {
          // no max-sub: |s| <= ~3 analytically, exp is safe; store raw exp
          bool valid = (j < i) | (l16 <= rl);  // diagonal-tile causal mask
          float e = __expf(sc[j][r]);
          ps[rl][j * 16 + l16] = (bf16_t)(valid ? e : 0.f);
        } else if (j == (i | 1)) {
          ps[rl][j * 16 + l16] = (bf16_t)0.f;  // zero-fill read range
        }
      }
    }
    f4_t o0 = zero4, o1 = zero4, osum = zero4;
    #pragma unroll
    for (int kk = 0; kk <= (i >> 1); ++kk) {     // skip all-zero K-tiles for i<2
      int k0 = kk * 32 + quad * 8;
      bf8_t ap  = *(const bf8_t*)&ps[l16][k0];
      bf8_t bv0 = *(const bf8_t*)&vt[l16][k0];
      bf8_t bv1 = *(const bf8_t*)&vt[16 + l16][k0];
      o0   = __builtin_amdgcn_mfma_f32_16x16x32_bf16(ap, bv0, o0, 0, 0, 0);
      o1   = __builtin_amdgcn_mfma_f32_16x16x32_bf16(ap, bv1, o1, 0, 0, 0);
      // D[m][n] = rowsum[m] for every n: each lane gets its row's denominator
      osum = __builtin_amdgcn_mfma_f32_16x16x32_bf16(ap, ones8, osum, 0, 0, 0);
    }
    #pragma unroll
    for (int r = 0; r < 4; ++r) {
      int row = 16 * i + quad * 4 + r;
      float inv = __builtin_amdgcn_rcpf(osum[r]);   // >= exp(diag) > 0
      ob[row * HD + l16]      = o0[r] * inv;
      ob[row * HD + 16 + l16] = o1[r] * inv;
    }
  };

  // ---------------- phase 1: pipelined projection ----------------
  load_half(0, 0);                   // x tile 0 first (critical HBM stream)
  #pragma unroll
  for (int t = 0; t < 24; ++t) wfr[t] = wf[t * 64 + lane];   // weights once (L2-hot)
  proj_tile(0);
  proj_tile(1);
  proj_tile(2);
  proj_tile(3);
  // ---------------- phase 2: scores -> softmax -> PV ----------------
  sm_tile(0);
  sm_tile(1);
  sm_tile(2);
  sm_tile(3);
}

extern "C" void kernel_launch(void* const* d_in, const int* in_sizes, int n_in,
                              void* d_out, int out_size, void* d_ws, size_t ws_size,
                              hipStream_t stream) {
  const float* x  = (const float*)d_in[0];
  const float* Wq = (const float*)d_in[1];
  const float* Wk = (const float*)d_in[2];
  const float* Wv = (const float*)d_in[3];
  float* out = (float*)d_out;
  bf16_t* wf = (bf16_t*)d_ws;                  // 12288 bf16 = 24 KB
  int B = in_sizes[0] / (TT * CC);             // 4096

  prep_weights<<<dim3(48), dim3(256), 0, stream>>>(Wq, Wk, Wv, wf);
  head_fused<<<dim3(B), dim3(64), 0, stream>>>(x, (const bf8_t*)wf, out);
}

// Round 5
// 224.518 us; speedup vs baseline: 1.0321x; 1.0321x over previous
//
#include <hip/hip_runtime.h>

// Head: fused single-head causal attention. Round 9: occupancy via LDS-shared
// weights. Round 7 (global weight reloads) and round 8 (forced VGPR bound ->
// wholesale array spill, VGPR_Count=84, WRITE_SIZE 3.3x) both failed to buy
// occupancy. This round removes the 96-VGPR weight array entirely: 256-thread
// blocks (4 waves, one batch element each) share ONE 24 KB LDS weight copy,
// read per-use as conflict-free ds_read_b128 frags. Per-wave LDS shrinks to
// 3.8 KB by holding K and V^T as register B-frags (16+16 VGPR), transposed
// through a small time-multiplexed scratch (same roundtrip trick as q and P).
// Block LDS 39,936 B; true VGPR ~140 under (256,3)=170 budget (margin ~30)
// -> 12 waves/CU (was 8). Schedule: proj pair -> sm pair, so V frags are
// fully projected before first use and q frags are short-lived.
// Softmax: no max-sub (|s|<~3), scale folded into Wq; denominator via
// ones-column MFMA row-sum; P stored unnormalized, O divided at the end.
//
// mfma_f32_16x16x32_bf16 layouts (HW-verified, guide §3):
//   A-frag: A[m = lane&15][k = quad*8 + j]
//   B-frag: B[k = quad*8 + j][n = lane&15]
//   C/D   : col = lane&15, row = quad*4 + reg

#define TT 64
#define CC 128
#define HD 32

typedef __bf16 bf16_t;
typedef __bf16 bf8_t __attribute__((ext_vector_type(8)));
typedef __bf16 bf4_t __attribute__((ext_vector_type(4)));
typedef float  f4_t  __attribute__((ext_vector_type(4)));

// d_ws: wf[(n6*4 + kk)*64 + lane] = 16-byte bf8 B-frag.
// n6 = 0..5 (q lo/hi, k lo/hi, v lo/hi), kk = 0..3 (K blocks of 32).
// Element j = Wsel[(kk*32 + (lane>>4)*8 + j)][(n6&1)*16 + (lane&15)].
// Q-frags (n6<2) pre-scaled by 1/sqrt(32).
__global__ __launch_bounds__(256) void prep_weights(
    const float* __restrict__ Wq, const float* __restrict__ Wk,
    const float* __restrict__ Wv, bf16_t* __restrict__ wf)
{
  int t = blockIdx.x * 256 + threadIdx.x;   // 0..12287
  int j    = t & 7;
  int lane = (t >> 3) & 63;
  int kt   = (t >> 9) & 3;
  int n6   = t >> 11;
  int k    = kt * 32 + (lane >> 4) * 8 + j;
  int col  = (n6 & 1) * 16 + (lane & 15);
  const float* W = (n6 >> 1) == 0 ? Wq : ((n6 >> 1) == 1 ? Wk : Wv);
  float v = W[k * HD + col];
  if (n6 < 2) v *= 0.17677669529663687f;    // fold 1/sqrt(32) into Wq
  wf[t] = (bf16_t)v;
}

__global__ __launch_bounds__(256, 3) void head_fused(
    const float* __restrict__ x, const float4* __restrict__ wf,
    float* __restrict__ out)
{
  __shared__ __align__(16) bf16_t wlds[12288];    // 24576 B weights (block-shared)
  __shared__ __align__(16) bf16_t qk[4][16][40];  //  5120 B q/k transpose scratch
  __shared__ __align__(16) bf16_t pv[4][1280];    // 10240 B v-scratch / P-strip (shared)
  // total 39936 B -> 4 blocks/CU by LDS; VGPR(<=170) -> 3 blocks = 12 waves/CU

  const int tid  = threadIdx.x;
  const int wv   = tid >> 6;         // wave 0..3 -> its own batch element
  const int lane = tid & 63;
  const int quad = lane >> 4;
  const int l16  = lane & 15;

  const int e = blockIdx.x * 4 + wv;
  const float* __restrict__ xblk = x + (size_t)e * (TT * CC);
  float* __restrict__ ob = out + (size_t)e * (TT * HD);

  const f4_t zero4 = {0.f, 0.f, 0.f, 0.f};

  float4 tf[4];                      // half-tile x staging (16 VGPR)
  bf8_t kB[4];                       // K B-frags, register-resident (16 VGPR)
  bf8_t vLo[2], vHi[2];              // V^T B-frags per 32-token pair (16 VGPR)

  // issue first x half-tile BEFORE weight staging (longest-latency stream first)
  auto load_half = [&](int i, int h) {
    #pragma unroll
    for (int u = 0; u < 2; ++u) {
      const float* s = xblk + (16 * i + l16) * CC + (2 * h + u) * 32 + quad * 8;
      tf[2 * u]     = *(const float4*)s;
      tf[2 * u + 1] = *(const float4*)(s + 4);
    }
  };
  load_half(0, 0);

  // ---- stage weights to LDS: 6 x (256 threads x 16 B), once per block ----
  #pragma unroll
  for (int u = 0; u < 6; ++u) {
    float4 w4 = wf[u * 256 + tid];
    *(float4*)&wlds[(u * 256 + tid) * 8] = w4;
  }
  __syncthreads();                   // only barrier; waves independent after

  bf16_t (* __restrict__ qks)[40] = qk[wv];
  bf16_t * __restrict__ pvb = pv[wv];

  // weight frag t: conflict-free ds_read_b128 (lane*16 B contiguous)
  auto wfrag = [&](int t) -> bf8_t {
    return *(const bf8_t*)&wlds[t * 512 + lane * 8];
  };
  auto cvt8 = [&](int u) -> bf8_t {
    float4 f0 = tf[2 * u], f1 = tf[2 * u + 1];
    bf8_t a;
    a[0] = (bf16_t)f0.x; a[1] = (bf16_t)f0.y; a[2] = (bf16_t)f0.z; a[3] = (bf16_t)f0.w;
    a[4] = (bf16_t)f1.x; a[5] = (bf16_t)f1.y; a[6] = (bf16_t)f1.z; a[7] = (bf16_t)f1.w;
    return a;
  };

  // precondition: half (i,0) in flight. Produces: aq (q A-frag, transient),
  // kB[i], and v half-pair written to vs scratch (pvb, [32][40] view).
  auto proj_tile = [&](int i, bf8_t& aqo) {
    f4_t acc[6];
    #pragma unroll
    for (int n = 0; n < 6; ++n) acc[n] = zero4;
    bf8_t a0 = cvt8(0), a1 = cvt8(1);     // waits on half (i,0)
    load_half(i, 1);
    #pragma unroll
    for (int n = 0; n < 6; ++n)
      acc[n] = __builtin_amdgcn_mfma_f32_16x16x32_bf16(a0, wfrag(n * 4 + 0), acc[n], 0, 0, 0);
    #pragma unroll
    for (int n = 0; n < 6; ++n)
      acc[n] = __builtin_amdgcn_mfma_f32_16x16x32_bf16(a1, wfrag(n * 4 + 1), acc[n], 0, 0, 0);
    bf8_t a2 = cvt8(0), a3 = cvt8(1);     // waits on half (i,1)
    if (i < 3) load_half(i + 1, 0);
    #pragma unroll
    for (int n = 0; n < 6; ++n)
      acc[n] = __builtin_amdgcn_mfma_f32_16x16x32_bf16(a2, wfrag(n * 4 + 2), acc[n], 0, 0, 0);
    #pragma unroll
    for (int n = 0; n < 6; ++n)
      acc[n] = __builtin_amdgcn_mfma_f32_16x16x32_bf16(a3, wfrag(n * 4 + 3), acc[n], 0, 0, 0);
    // q -> scratch (C-layout) -> A-frag registers
    #pragma unroll
    for (int r = 0; r < 4; ++r) {
      int rl = quad * 4 + r;               // C/D: row = quad*4 + reg
      qks[rl][l16]      = (bf16_t)acc[0][r];
      qks[rl][16 + l16] = (bf16_t)acc[1][r];
    }
    aqo = *(const bf8_t*)&qks[l16][quad * 8];
    // k -> same scratch (in-order DS: q read precedes overwrite) -> B-frag regs
    #pragma unroll
    for (int r = 0; r < 4; ++r) {
      int rl = quad * 4 + r;
      qks[rl][l16]      = (bf16_t)acc[2][r];
      qks[rl][16 + l16] = (bf16_t)acc[3][r];
    }
    kB[i] = *(const bf8_t*)&qks[l16][quad * 8];
    // v -> vs scratch half (transpose-store), tokens 16*(i&1)..+15 of the pair
    bf4_t v0 = { (bf16_t)acc[4][0], (bf16_t)acc[4][1], (bf16_t)acc[4][2], (bf16_t)acc[4][3] };
    bf4_t v1 = { (bf16_t)acc[5][0], (bf16_t)acc[5][1], (bf16_t)acc[5][2], (bf16_t)acc[5][3] };
    *(bf4_t*)&pvb[l16 * 40        + 16 * (i & 1) + quad * 4] = v0;
    *(bf4_t*)&pvb[(16 + l16) * 40 + 16 * (i & 1) + quad * 4] = v1;
  };

  // after a proj pair: lift the pair's V^T B-frags out of vs scratch
  auto read_v = [&](int p) {
    vLo[p] = *(const bf8_t*)&pvb[l16 * 40        + quad * 8];
    vHi[p] = *(const bf8_t*)&pvb[(16 + l16) * 40 + quad * 8];
  };

  bf8_t ones8;
  #pragma unroll
  for (int t = 0; t < 8; ++t) ones8[t] = (bf16_t)1.0f;

  // scores -> exp (unnormalized, bf16, P-strip view of pvb) -> PV from
  // register V frags + ones-MFMA row-sum -> divide. pvb P-layout: [16][72].
  auto sm_tile = [&](int i, bf8_t aqv) {
    f4_t sc[4];
    #pragma unroll
    for (int j = 0; j < 4; ++j) {
      sc[j] = zero4;
      if (j <= i)
        sc[j] = __builtin_amdgcn_mfma_f32_16x16x32_bf16(aqv, kB[j], zero4, 0, 0, 0);
    }
    #pragma unroll
    for (int r = 0; r < 4; ++r) {
      int rl = quad * 4 + r;
      #pragma unroll
      for (int j = 0; j < 4; ++j) {
        if (j <= i) {
          // no max-sub: |s| <= ~3 analytically, exp is safe; store raw exp
          bool valid = (j < i) | (l16 <= rl);  // diagonal-tile causal mask
          float ev = __expf(sc[j][r]);
          pvb[rl * 72 + j * 16 + l16] = (bf16_t)(valid ? ev : 0.f);
        } else if (j == (i | 1)) {
          pvb[rl * 72 + j * 16 + l16] = (bf16_t)0.f;  // zero-fill read range
        }
      }
    }
    f4_t o0 = zero4, o1 = zero4, osum = zero4;
    #pragma unroll
    for (int kk = 0; kk < 2; ++kk) {
      if (kk <= (i >> 1)) {                    // skip all-zero K-tiles for i<2
        bf8_t ap = *(const bf8_t*)&pvb[l16 * 72 + kk * 32 + quad * 8];
        o0   = __builtin_amdgcn_mfma_f32_16x16x32_bf16(ap, vLo[kk], o0, 0, 0, 0);
        o1   = __builtin_amdgcn_mfma_f32_16x16x32_bf16(ap, vHi[kk], o1, 0, 0, 0);
        // D[m][n] = rowsum[m] for every n: each lane gets its row's denominator
        osum = __builtin_amdgcn_mfma_f32_16x16x32_bf16(ap, ones8, osum, 0, 0, 0);
      }
    }
    #pragma unroll
    for (int r = 0; r < 4; ++r) {
      int row = 16 * i + quad * 4 + r;
      float inv = __builtin_amdgcn_rcpf(osum[r]);   // >= exp(diag) > 0
      ob[row * HD + l16]      = o0[r] * inv;
      ob[row * HD + 16 + l16] = o1[r] * inv;
    }
  };

  // ---- schedule: proj pair -> lift V -> sm pair (q frags short-lived) ----
  bf8_t aq0, aq1;
  proj_tile(0, aq0);
  proj_tile(1, aq1);
  read_v(0);                         // tokens 0..31 fully projected
  sm_tile(0, aq0);
  sm_tile(1, aq1);
  proj_tile(2, aq0);                 // vs scratch reuse: P from sm1 is dead
  proj_tile(3, aq1);
  read_v(1);                         // tokens 32..63
  sm_tile(2, aq0);
  sm_tile(3, aq1);
}

extern "C" void kernel_launch(void* const* d_in, const int* in_sizes, int n_in,
                              void* d_out, int out_size, void* d_ws, size_t ws_size,
                              hipStream_t stream) {
  const float* x  = (const float*)d_in[0];
  const float* Wq = (const float*)d_in[1];
  const float* Wk = (const float*)d_in[2];
  const float* Wv = (const float*)d_in[3];
  float* out = (float*)d_out;
  bf16_t* wf = (bf16_t*)d_ws;                  // 12288 bf16 = 24 KB
  int B = in_sizes[0] / (TT * CC);             // 4096

  prep_weights<<<dim3(48), dim3(256), 0, stream>>>(Wq, Wk, Wv, wf);
  head_fused<<<dim3(B / 4), dim3(256), 0, stream>>>(x, (const float4*)wf, out);
}

// Round 7
// 208.914 us; speedup vs baseline: 1.1092x; 1.0747x over previous
//
#include <hip/hip_runtime.h>

// Head: fused single-head causal attention. Round 10 (resubmit — round 6's
// bench was an infra failure: "container failed twice", no counters).
// Occupancy via NATURAL register demand (no forced launch bounds — rounds
// 7/8/9 proved min-waves forcing => wholesale array spills). Structure =
// round 6 (known-good, head=61.3us after the 145us fixed-overhead
// calibration) with two register cuts so the allocator can land <=168 VGPR
// on its own (3 waves/EU at the hardware's natural occupancy rule):
//   (a) q stays in LDS qs (r6 style) instead of aq[4] regs   (-16 VGPR)
//   (b) x staging shrunk to a quarter-tile qf[2] (2x dwordx4) (-8 VGPR)
// Peak est ~156: wfr 96 + qf 8 + acc 24 + a-frag 8 + addressing ~20.
// LDS 17152 B -> 9 blocks/CU; declared (64,2) = safe 256 budget, no cliff.
// Softmax: no max-sub (|s|<~3), scale folded into Wq; denominator via
// ones-column MFMA row-sum; P stored unnormalized, O divided at the end.
//
// mfma_f32_16x16x32_bf16 layouts (HW-verified, guide §3):
//   A-frag: A[m = lane&15][k = quad*8 + j]
//   B-frag: B[k = quad*8 + j][n = lane&15]
//   C/D   : col = lane&15, row = quad*4 + reg

#define TT 64
#define CC 128
#define HD 32

typedef __bf16 bf16_t;
typedef __bf16 bf8_t __attribute__((ext_vector_type(8)));
typedef __bf16 bf4_t __attribute__((ext_vector_type(4)));
typedef float  f4_t  __attribute__((ext_vector_type(4)));

// d_ws: wf[(n6*4 + kk)*64 + lane] = 16-byte bf8 B-frag.
// n6 = 0..5 (q lo/hi, k lo/hi, v lo/hi), kk = 0..3 (K blocks of 32).
// Element j = Wsel[(kk*32 + (lane>>4)*8 + j)][(n6&1)*16 + (lane&15)].
// Q-frags (n6<2) pre-scaled by 1/sqrt(32).
__global__ __launch_bounds__(256) void prep_weights(
    const float* __restrict__ Wq, const float* __restrict__ Wk,
    const float* __restrict__ Wv, bf16_t* __restrict__ wf)
{
  int t = blockIdx.x * 256 + threadIdx.x;   // 0..12287
  int j    = t & 7;
  int lane = (t >> 3) & 63;
  int kt   = (t >> 9) & 3;
  int n6   = t >> 11;
  int k    = kt * 32 + (lane >> 4) * 8 + j;
  int col  = (n6 & 1) * 16 + (lane & 15);
  const float* W = (n6 >> 1) == 0 ? Wq : ((n6 >> 1) == 1 ? Wk : Wv);
  float v = W[k * HD + col];
  if (n6 < 2) v *= 0.17677669529663687f;    // fold 1/sqrt(32) into Wq
  wf[t] = (bf16_t)v;
}

__global__ __launch_bounds__(64, 2) void head_fused(
    const float* __restrict__ x, const bf8_t* __restrict__ wf,
    float* __restrict__ out)
{
  __shared__ __align__(16) bf16_t qs[TT][40];   // q[row][d]        5120 B
  __shared__ __align__(16) bf16_t ks[TT][40];   // k[row][d]        5120 B
  __shared__ __align__(16) bf16_t vt[HD][72];   // v^T[d][row]      4608 B
  __shared__ __align__(16) bf16_t ps[16][72];   // P strip (unnorm) 2304 B
  // total 17152 B -> 9 one-wave blocks/CU by LDS; VGPR target <=168 (3/EU)

  const int lane = threadIdx.x;      // 0..63, one wave
  const int quad = lane >> 4;
  const int l16  = lane & 15;
  const int b    = blockIdx.x;
  const float* __restrict__ xblk = x + (size_t)b * (TT * CC);
  float* __restrict__ ob = out + (size_t)b * (TT * HD);

  const f4_t zero4 = {0.f, 0.f, 0.f, 0.f};

  bf8_t wfr[24];                     // resident weight B-frags (96 VGPR)
  float4 qf[2];                      // QUARTER-tile x staging (8 VGPR)

  // issue quarter-tile loads: lane covers 32 B of row (16i+l16), K-block p
  auto load_q = [&](int i, int p) {
    const float* s = xblk + (16 * i + l16) * CC + p * 32 + quad * 8;
    qf[0] = *(const float4*)s;
    qf[1] = *(const float4*)(s + 4);
  };
  auto cvtq = [&]() -> bf8_t {       // waits on qf, frees it for re-issue
    float4 f0 = qf[0], f1 = qf[1];
    bf8_t a;
    a[0] = (bf16_t)f0.x; a[1] = (bf16_t)f0.y; a[2] = (bf16_t)f0.z; a[3] = (bf16_t)f0.w;
    a[4] = (bf16_t)f1.x; a[5] = (bf16_t)f1.y; a[6] = (bf16_t)f1.z; a[7] = (bf16_t)f1.w;
    return a;
  };

  // precondition: quarter (i,0) in flight on entry.
  auto proj_tile = [&](int i) {
    f4_t acc[6];
    #pragma unroll
    for (int n = 0; n < 6; ++n) acc[n] = zero4;
    #pragma unroll
    for (int p = 0; p < 4; ++p) {
      bf8_t a = cvtq();                      // WAR on qf keeps order safe
      if (p < 3)      load_q(i, p + 1);      // re-issue freed buffer
      else if (i < 3) load_q(i + 1, 0);
      #pragma unroll
      for (int n = 0; n < 6; ++n)
        acc[n] = __builtin_amdgcn_mfma_f32_16x16x32_bf16(a, wfr[n * 4 + p], acc[n], 0, 0, 0);
    }
    // stores: q -> qs, k -> ks (transpose via C-layout), v -> vt
    #pragma unroll
    for (int r = 0; r < 4; ++r) {
      int row = 16 * i + quad * 4 + r;       // C/D: row = quad*4 + reg
      qs[row][l16]      = (bf16_t)acc[0][r];
      qs[row][16 + l16] = (bf16_t)acc[1][r];
      ks[row][l16]      = (bf16_t)acc[2][r];
      ks[row][16 + l16] = (bf16_t)acc[3][r];
    }
    bf4_t v0 = { (bf16_t)acc[4][0], (bf16_t)acc[4][1], (bf16_t)acc[4][2], (bf16_t)acc[4][3] };
    bf4_t v1 = { (bf16_t)acc[5][0], (bf16_t)acc[5][1], (bf16_t)acc[5][2], (bf16_t)acc[5][3] };
    *(bf4_t*)&vt[l16][16 * i + quad * 4]      = v0;   // tokens quad*4..+3 contiguous
    *(bf4_t*)&vt[16 + l16][16 * i + quad * 4] = v1;
  };

  // scores -> exp (unnormalized, bf16) -> PV + ones-MFMA row-sum -> divide.
  // no barrier anywhere: single wave, DS ops in-order (compiler lgkmcnt waits)
  bf8_t ones8;
  #pragma unroll
  for (int t = 0; t < 8; ++t) ones8[t] = (bf16_t)1.0f;

  auto sm_tile = [&](int i) {
    f4_t sc[4];
    bf8_t aq = *(const bf8_t*)&qs[16 * i + l16][quad * 8];   // scale pre-folded
    #pragma unroll
    for (int j = 0; j < 4; ++j) {
      sc[j] = zero4;
      if (j <= i) {
        bf8_t bk = *(const bf8_t*)&ks[16 * j + l16][quad * 8];
        sc[j] = __builtin_amdgcn_mfma_f32_16x16x32_bf16(aq, bk, zero4, 0, 0, 0);
      }
    }
    #pragma unroll
    for (int r = 0; r < 4; ++r) {
      int rl = quad * 4 + r;
      #pragma unroll
      for (int j = 0; j < 4; ++j) {
        if (j <= i) {
          // no max-sub: |s| <= ~3 analytically, exp is safe; store raw exp
          bool valid = (j < i) | (l16 <= rl);  // diagonal-tile causal mask
          float e = __expf(sc[j][r]);
          ps[rl][j * 16 + l16] = (bf16_t)(valid ? e : 0.f);
        } else if (j == (i | 1)) {
          ps[rl][j * 16 + l16] = (bf16_t)0.f;  // zero-fill read range
        }
      }
    }
    f4_t o0 = zero4, o1 = zero4, osum = zero4;
    #pragma unroll
    for (int kk = 0; kk <= (i >> 1); ++kk) {     // skip all-zero K-tiles for i<2
      int k0 = kk * 32 + quad * 8;
      bf8_t ap  = *(const bf8_t*)&ps[l16][k0];
      bf8_t bv0 = *(const bf8_t*)&vt[l16][k0];
      bf8_t bv1 = *(const bf8_t*)&vt[16 + l16][k0];
      o0   = __builtin_amdgcn_mfma_f32_16x16x32_bf16(ap, bv0, o0, 0, 0, 0);
      o1   = __builtin_amdgcn_mfma_f32_16x16x32_bf16(ap, bv1, o1, 0, 0, 0);
      // D[m][n] = rowsum[m] for every n: each lane gets its row's denominator
      osum = __builtin_amdgcn_mfma_f32_16x16x32_bf16(ap, ones8, osum, 0, 0, 0);
    }
    #pragma unroll
    for (int r = 0; r < 4; ++r) {
      int row = 16 * i + quad * 4 + r;
      float inv = __builtin_amdgcn_rcpf(osum[r]);   // >= exp(diag) > 0
      ob[row * HD + l16]      = o0[r] * inv;
      ob[row * HD + 16 + l16] = o1[r] * inv;
    }
  };

  // ---------------- phase 1: pipelined projection ----------------
  load_q(0, 0);                      // x quarter (0,0) first (oldest in queue)
  #pragma unroll
  for (int t = 0; t < 24; ++t) wfr[t] = wf[t * 64 + lane];   // weights once (L2-hot)
  proj_tile(0);
  proj_tile(1);
  proj_tile(2);
  proj_tile(3);
  // ---------------- phase 2: scores -> softmax -> PV ----------------
  sm_tile(0);
  sm_tile(1);
  sm_tile(2);
  sm_tile(3);
}

extern "C" void kernel_launch(void* const* d_in, const int* in_sizes, int n_in,
                              void* d_out, int out_size, void* d_ws, size_t ws_size,
                              hipStream_t stream) {
  const float* x  = (const float*)d_in[0];
  const float* Wq = (const float*)d_in[1];
  const float* Wk = (const float*)d_in[2];
  const float* Wv = (const float*)d_in[3];
  float* out = (float*)d_out;
  bf16_t* wf = (bf16_t*)d_ws;                  // 12288 bf16 = 24 KB
  int B = in_sizes[0] / (TT * CC);             // 4096

  prep_weights<<<dim3(48), dim3(256), 0, stream>>>(Wq, Wk, Wv, wf);
  head_fused<<<dim3(B), dim3(64), 0, stream>>>(x, (const bf8_t*)wf, out);
}

// Round 8
// 206.148 us; speedup vs baseline: 1.1241x; 1.0134x over previous
//
#include <hip/hip_runtime.h>

// Head: fused single-head causal attention. Round 11: cooperative 4-wave
// block. Root cause of rounds 7-10's failed occupancy pushes: the 96-VGPR
// resident weight array in EVERY wave. Fix: one 256-thread block per batch
// element; weights staged ONCE into block LDS (24 KB) and read per-use as
// conflict-free ds_read_b128 frags; each of the 4 waves projects one 16-row
// tile (q kept in registers as C-frags) and runs one sm_tile. Phase-2
// P-strips ALIAS the weight LDS region (dead after phase 1, barrier-
// separated). LDS = 24576(w) + 5120(ks) + 4608(vt) = 34304 B -> 4 blocks/CU;
// per-wave VGPR ~80-110 (natural, no forced bounds) -> 16 waves/CU, 2x TLP,
// and ~4x shorter per-element critical path. Two __syncthreads total.
// Softmax: no max-sub (|s|<~3), scale folded into Wq; denominator via
// ones-column MFMA row-sum; P stored unnormalized, O divided at the end.
//
// mfma_f32_16x16x32_bf16 layouts (HW-verified, guide §3):
//   A-frag: A[m = lane&15][k = quad*8 + j]
//   B-frag: B[k = quad*8 + j][n = lane&15]
//   C/D   : col = lane&15, row = quad*4 + reg

#define TT 64
#define CC 128
#define HD 32

typedef __bf16 bf16_t;
typedef __bf16 bf8_t __attribute__((ext_vector_type(8)));
typedef __bf16 bf4_t __attribute__((ext_vector_type(4)));
typedef float  f4_t  __attribute__((ext_vector_type(4)));

// d_ws: wf[(n6*4 + kk)*64 + lane] = 16-byte bf8 B-frag.
// n6 = 0..5 (q lo/hi, k lo/hi, v lo/hi), kk = 0..3 (K blocks of 32).
// Element j = Wsel[(kk*32 + (lane>>4)*8 + j)][(n6&1)*16 + (lane&15)].
// Q-frags (n6<2) pre-scaled by 1/sqrt(32).
__global__ __launch_bounds__(256) void prep_weights(
    const float* __restrict__ Wq, const float* __restrict__ Wk,
    const float* __restrict__ Wv, bf16_t* __restrict__ wf)
{
  int t = blockIdx.x * 256 + threadIdx.x;   // 0..12287
  int j    = t & 7;
  int lane = (t >> 3) & 63;
  int kt   = (t >> 9) & 3;
  int n6   = t >> 11;
  int k    = kt * 32 + (lane >> 4) * 8 + j;
  int col  = (n6 & 1) * 16 + (lane & 15);
  const float* W = (n6 >> 1) == 0 ? Wq : ((n6 >> 1) == 1 ? Wk : Wv);
  float v = W[k * HD + col];
  if (n6 < 2) v *= 0.17677669529663687f;    // fold 1/sqrt(32) into Wq
  wf[t] = (bf16_t)v;
}

__global__ __launch_bounds__(256) void head_fused(
    const float* __restrict__ x, const float4* __restrict__ wf,
    float* __restrict__ out)
{
  __shared__ __align__(16) bf16_t wlds[12288];  // 24576 B weights; phase 2:
                                                //   first 9216 B = P strips
  __shared__ __align__(16) bf16_t ks[TT][40];   // k[row][d]        5120 B
  __shared__ __align__(16) bf16_t vt[HD][72];   // v^T[d][row]      4608 B
  // total 34304 B -> 4 blocks/CU by LDS; VGPR target <=128 -> 16 waves/CU

  const int tid  = threadIdx.x;
  const int wv   = tid >> 6;         // wave 0..3 = tile index within element
  const int lane = tid & 63;
  const int quad = lane >> 4;
  const int l16  = lane & 15;
  const int b    = blockIdx.x;       // one block per batch element
  const float* __restrict__ xblk = x + (size_t)b * (TT * CC);
  float* __restrict__ ob = out + (size_t)b * (TT * HD);

  const f4_t zero4 = {0.f, 0.f, 0.f, 0.f};

  float4 qf[2];                      // quarter-tile x staging (8 VGPR)

  // wave loads quarters of ITS 16-row tile: lane covers 32 B of row 16wv+l16
  auto load_q = [&](int p) {
    const float* s = xblk + (16 * wv + l16) * CC + p * 32 + quad * 8;
    qf[0] = *(const float4*)s;
    qf[1] = *(const float4*)(s + 4);
  };
  auto cvtq = [&]() -> bf8_t {       // waits on qf, frees it for re-issue
    float4 f0 = qf[0], f1 = qf[1];
    bf8_t a;
    a[0] = (bf16_t)f0.x; a[1] = (bf16_t)f0.y; a[2] = (bf16_t)f0.z; a[3] = (bf16_t)f0.w;
    a[4] = (bf16_t)f1.x; a[5] = (bf16_t)f1.y; a[6] = (bf16_t)f1.z; a[7] = (bf16_t)f1.w;
    return a;
  };

  // ---- issue first x quarter, then stage weights to LDS (once/block) ----
  load_q(0);
  #pragma unroll
  for (int u = 0; u < 6; ++u) {                  // 6 x (256 thr x 16 B) = 24 KB
    float4 w4 = wf[u * 256 + tid];
    *(float4*)&wlds[(size_t)(u * 256 + tid) * 8] = w4;
  }
  __syncthreads();                   // weights visible to all waves

  // weight frag t: conflict-free ds_read_b128 (lane*16 B contiguous)
  auto wfrag = [&](int t) -> bf8_t {
    return *(const bf8_t*)&wlds[t * 512 + lane * 8];
  };

  // ---------------- phase 1: each wave projects its own tile ----------------
  f4_t acc[6];
  #pragma unroll
  for (int n = 0; n < 6; ++n) acc[n] = zero4;
  #pragma unroll
  for (int p = 0; p < 4; ++p) {
    bf8_t a = cvtq();                          // WAR on qf keeps order safe
    if (p < 3) load_q(p + 1);                  // re-issue freed buffer
    #pragma unroll
    for (int n = 0; n < 6; ++n)
      acc[n] = __builtin_amdgcn_mfma_f32_16x16x32_bf16(a, wfrag(n * 4 + p), acc[n], 0, 0, 0);
  }
  // k -> ks, v -> vt (shared); q stays in registers as bf16 C-frags
  #pragma unroll
  for (int r = 0; r < 4; ++r) {
    int row = 16 * wv + quad * 4 + r;          // C/D: row = quad*4 + reg
    ks[row][l16]      = (bf16_t)acc[2][r];
    ks[row][16 + l16] = (bf16_t)acc[3][r];
  }
  bf4_t v0 = { (bf16_t)acc[4][0], (bf16_t)acc[4][1], (bf16_t)acc[4][2], (bf16_t)acc[4][3] };
  bf4_t v1 = { (bf16_t)acc[5][0], (bf16_t)acc[5][1], (bf16_t)acc[5][2], (bf16_t)acc[5][3] };
  *(bf4_t*)&vt[l16][16 * wv + quad * 4]      = v0;   // tokens quad*4..+3 contiguous
  *(bf4_t*)&vt[16 + l16][16 * wv + quad * 4] = v1;
  bf4_t qc0 = { (bf16_t)acc[0][0], (bf16_t)acc[0][1], (bf16_t)acc[0][2], (bf16_t)acc[0][3] };
  bf4_t qc1 = { (bf16_t)acc[1][0], (bf16_t)acc[1][1], (bf16_t)acc[1][2], (bf16_t)acc[1][3] };
  __syncthreads();                   // k/v visible; weight region now dead

  // ---------------- phase 2: wave wv runs sm_tile(wv) ----------------
  // P strip aliases the (dead) weight LDS: 4 x [16][72] x 2 B = 9216 B
  bf16_t* __restrict__ psw = wlds + wv * 1152;

  // q C-layout -> A-frag via own strip (in-order DS within the wave)
  #pragma unroll
  for (int r = 0; r < 4; ++r) {
    psw[(quad * 4 + r) * 72 + l16]      = qc0[r];
    psw[(quad * 4 + r) * 72 + 16 + l16] = qc1[r];
  }
  bf8_t aq = *(const bf8_t*)&psw[l16 * 72 + quad * 8];   // scale pre-folded

  bf8_t ones8;
  #pragma unroll
  for (int t = 0; t < 8; ++t) ones8[t] = (bf16_t)1.0f;

  const int i = wv;
  f4_t sc[4];
  #pragma unroll
  for (int j = 0; j < 4; ++j) {
    sc[j] = zero4;
    if (j <= i) {
      bf8_t bk = *(const bf8_t*)&ks[16 * j + l16][quad * 8];
      sc[j] = __builtin_amdgcn_mfma_f32_16x16x32_bf16(aq, bk, zero4, 0, 0, 0);
    }
  }
  #pragma unroll
  for (int r = 0; r < 4; ++r) {
    int rl = quad * 4 + r;
    #pragma unroll
    for (int j = 0; j < 4; ++j) {
      if (j <= i) {
        // no max-sub: |s| <= ~3 analytically, exp is safe; store raw exp
        bool valid = (j < i) | (l16 <= rl);    // diagonal-tile causal mask
        float e = __expf(sc[j][r]);
        psw[rl * 72 + j * 16 + l16] = (bf16_t)(valid ? e : 0.f);
      } else if (j == (i | 1)) {
        psw[rl * 72 + j * 16 + l16] = (bf16_t)0.f;  // zero-fill read range
      }
    }
  }
  f4_t o0 = zero4, o1 = zero4, osum = zero4;
  #pragma unroll
  for (int kk = 0; kk < 2; ++kk) {
    if (kk <= (i >> 1)) {                      // skip all-zero K-tiles for i<2
      int k0 = kk * 32 + quad * 8;
      bf8_t ap  = *(const bf8_t*)&psw[l16 * 72 + k0];
      bf8_t bv0 = *(const bf8_t*)&vt[l16][k0];
      bf8_t bv1 = *(const bf8_t*)&vt[16 + l16][k0];
      o0   = __builtin_amdgcn_mfma_f32_16x16x32_bf16(ap, bv0, o0, 0, 0, 0);
      o1   = __builtin_amdgcn_mfma_f32_16x16x32_bf16(ap, bv1, o1, 0, 0, 0);
      // D[m][n] = rowsum[m] for every n: each lane gets its row's denominator
      osum = __builtin_amdgcn_mfma_f32_16x16x32_bf16(ap, ones8, osum, 0, 0, 0);
    }
  }
  #pragma unroll
  for (int r = 0; r < 4; ++r) {
    int row = 16 * i + quad * 4 + r;
    float inv = __builtin_amdgcn_rcpf(osum[r]);   // >= exp(diag) > 0
    ob[row * HD + l16]      = o0[r] * inv;
    ob[row * HD + 16 + l16] = o1[r] * inv;
  }
}

extern "C" void kernel_launch(void* const* d_in, const int* in_sizes, int n_in,
                              void* d_out, int out_size, void* d_ws, size_t ws_size,
                              hipStream_t stream) {
  const float* x  = (const float*)d_in[0];
  const float* Wq = (const float*)d_in[1];
  const float* Wk = (const float*)d_in[2];
  const float* Wv = (const float*)d_in[3];
  float* out = (float*)d_out;
  bf16_t* wf = (bf16_t*)d_ws;                  // 12288 bf16 = 24 KB
  int B = in_sizes[0] / (TT * CC);             // 4096

  prep_weights<<<dim3(48), dim3(256), 0, stream>>>(Wq, Wk, Wv, wf);
  head_fused<<<dim3(B), dim3(256), 0, stream>>>(x, (const float4*)wf, out);
}